// Round 5
// baseline (532.970 us; speedup 1.0000x reference)
//
#include <hip/hip_runtime.h>
#include <hip/hip_fp16.h>

typedef unsigned int uint;
typedef unsigned short ushort;

typedef __attribute__((ext_vector_type(8))) _Float16 f16x8;
typedef __attribute__((ext_vector_type(4))) float f32x4;

#define TOK 256
#define OUTF 11008
#define INF 4096
#define BM 256
#define BN 64
#define NT2 172  // OUTF / BN

__device__ __constant__ float NF4_TBL[16] = {
    -1.0f, -0.6961928009986877f, -0.5250730514526367f, -0.39491748809814453f,
    -0.28444138169288635f, -0.18477343022823334f, -0.09105003625154495f, 0.0f,
    0.07958029955625534f, 0.16093020141124725f, 0.24611230194568634f,
    0.33791524171829224f, 0.44070982933044434f, 0.5626170039176941f,
    0.7229568362236023f, 1.0f};

__device__ __forceinline__ ushort f2h(float f) {
  return __half_as_ushort(__float2half(f));
}

// async global->LDS, 16B per lane; lds base wave-uniform + lane*16
__device__ __forceinline__ void async_cp16(const void* g, void* l) {
  __builtin_amdgcn_global_load_lds(
      (const __attribute__((address_space(1))) uint*)g,
      (__attribute__((address_space(3))) uint*)l, 16, 0, 0);
}

// table value via VGPR crossbar (conflict-free); lanes 0..15 of every 16 hold the table
__device__ __forceinline__ float nf4v(int c, int tbits) {
  return __int_as_float(__builtin_amdgcn_ds_bpermute(c << 2, tbits));
}

// 4 raw codes -> 4 scaled halfs (8B)
__device__ __forceinline__ uint2 dq4(int4 c, __half2 ax2, int tbits) {
  __half2 h0 = __floats2half2_rn(nf4v(c.x, tbits), nf4v(c.y, tbits));
  __half2 h1 = __floats2half2_rn(nf4v(c.z, tbits), nf4v(c.w, tbits));
  h0 = __hmul2(h0, ax2);
  h1 = __hmul2(h1, ax2);
  union { __half2 h[2]; uint2 u; } r;
  r.h[0] = h0; r.h[1] = h1;
  return r.u;
}

// LDS-visibility barrier, NO vmcnt drain (global loads target registers and
// may stay in flight across the barrier = counted-vmcnt pipeline)
__device__ __forceinline__ void step_barrier() {
  asm volatile("s_waitcnt lgkmcnt(0)" ::: "memory");
  __builtin_amdgcn_s_barrier();
}

// kernel 1 (merged prep + xa):
// blocks [0,256): x fp32 -> f16 in MFMA-fragment layout xf; lora_B -> f16 padded.
// blocks [256,512): xa2[m][j] = f16( 2 * sum_k x[m][k]*lora_A[j][k] ), [TOK,64] padded.
__global__ __launch_bounds__(1024)
void prep_kernel(const float* __restrict__ x, uint4* __restrict__ xf4,
                 const float4* __restrict__ lB4, ushort4* __restrict__ lBh4,
                 const float* __restrict__ lA, ushort* __restrict__ xa2) {
  if (blockIdx.x < 256) {
    const int stride = 256 * 1024;
    const int t0 = blockIdx.x * 1024 + threadIdx.x;
    // x -> fragment layout: one 16B frag per iteration (8 halfs along k of one row)
    for (int f = t0; f < TOK * INF / 8; f += stride) {
      int l = f & 63;
      int rlo = l & 15, chunk = l >> 4;
      int ms = (f >> 6) & 7;      // mt*2 + ks2
      int mt = ms >> 1, ks2 = ms & 1;
      int w = (f >> 9) & 3;
      int kb = f >> 11;
      int m = w * 64 + mt * 16 + rlo;
      int k0 = kb * 64 + (ks2 * 4 + chunk) * 8;
      const float4* src = (const float4*)(x + (size_t)m * INF + k0);
      float4 v0 = src[0], v1 = src[1];
      union { ushort4 h[2]; uint4 u; } pk;
      pk.h[0].x = f2h(v0.x); pk.h[0].y = f2h(v0.y); pk.h[0].z = f2h(v0.z); pk.h[0].w = f2h(v0.w);
      pk.h[1].x = f2h(v1.x); pk.h[1].y = f2h(v1.y); pk.h[1].z = f2h(v1.z); pk.h[1].w = f2h(v1.w);
      xf4[f] = pk.u;
    }
    for (int i = t0; i < OUTF * 16; i += stride) {
      int n = i >> 4, jq = i & 15;
      ushort4 o = {0, 0, 0, 0};
      if (jq < 4) {
        float4 v = lB4[n * 4 + jq];
        o.x = f2h(v.x); o.y = f2h(v.y); o.z = f2h(v.z); o.w = f2h(v.w);
      }
      lBh4[i] = o;
    }
  } else {
    const int m = blockIdx.x - 256;
    const int t = threadIdx.x;
    const float4* x4 = (const float4*)(x + (size_t)m * INF);
    const float4* lA4 = (const float4*)lA;
    float4 xv = x4[t];
    float acc[16];
#pragma unroll
    for (int j = 0; j < 16; ++j) {
      float4 a = lA4[j * (INF / 4) + t];
      acc[j] = xv.x * a.x + xv.y * a.y + xv.z * a.z + xv.w * a.w;
    }
#pragma unroll
    for (int j = 0; j < 16; ++j)
#pragma unroll
      for (int s = 32; s > 0; s >>= 1) acc[j] += __shfl_xor(acc[j], s, 64);
    __shared__ float red[16][16];
    const int w = t >> 6, l = t & 63;
    if (l == 0) {
#pragma unroll
      for (int j = 0; j < 16; ++j) red[w][j] = acc[j];
    }
    __syncthreads();
    if (t < 64) {
      ushort v = 0;
      if (t < 16) {
        float s = 0.f;
#pragma unroll
        for (int w2 = 0; w2 < 16; ++w2) s += red[w2][t];
        v = f2h(2.0f * s);
      }
      xa2[m * 64 + t] = v;
    }
  }
}

// kernel 2: fused dequant GEMM, register-pipelined (R3 structure).
// launch_bounds(256,4): cap 128 VGPR (R3 used 116) -> 4 blocks/CU resident, so
// independent barrier groups co-schedule and fill each other's stalls.
// Q loads issued at PHASE START (registers dead there) -> extra latency cover.
// ks=8 K-split (nst=8) for grid 1376 ~ 5.4 blocks/CU demand.
// Partials written as f16 when split (halves epilogue + reduce traffic).
__global__ __launch_bounds__(256, 4)
void gemm_kernel(const int* __restrict__ qc, const float* __restrict__ am,
                 const ushort* __restrict__ xf, const ushort* __restrict__ lBh,
                 const ushort* __restrict__ xa2, float* __restrict__ dest32,
                 ushort* __restrict__ dest16, int nst, int fp16out) {
  __shared__ ushort Bbuf[2][64 * 64];  // 2 x 8 KB, octet-swizzled
  __shared__ float Qax[4096];          // 16 KB: full absmax rows [kb>>2][64 rows][kb&3]

  const int tid = threadIdx.x;
  const int w = tid >> 6;
  const int l = tid & 63;
  const int chunk = l >> 4;  // 0..3
  const int rlo = l & 15;
  const int split = blockIdx.x / NT2;
  const int ntile = blockIdx.x - split * NT2;
  const int n0 = ntile * BN;
  const int kb0 = split * nst;  // in 64-k blocks

  const int tbits = __float_as_int(NF4_TBL[l & 15]);

  // raw-q geometry (coalesced): per pass p, row r = p*16 + (tid>>4),
  // chunk qch = tid&15 -> int4 = 4 codes
  const int qrg = tid >> 4;  // 0..15
  const int qch = tid & 15;  // 0..15
  const int* qbase[4];
  int bdst[4];
#pragma unroll
  for (int p = 0; p < 4; ++p) {
    int r = p * 16 + qrg;
    qbase[p] = qc + (size_t)(n0 + r) * INF + kb0 * 64 + qch * 4;
    bdst[p] = r * 64 + (((qch >> 1) ^ (r & 7)) << 3) + (qch & 1) * 4;
  }

  // b-frag LDS read offsets (swizzle-matched)
  int boff[2][4];
#pragma unroll
  for (int ks2 = 0; ks2 < 2; ++ks2)
#pragma unroll
    for (int nt = 0; nt < 4; ++nt)
      boff[ks2][nt] = (nt * 16 + rlo) * 64 + (((ks2 * 4 + chunk) ^ (rlo & 7)) << 3);

  f32x4 acc[4][4];
#pragma unroll
  for (int mt = 0; mt < 4; ++mt)
#pragma unroll
    for (int nt = 0; nt < 4; ++nt) acc[mt][nt] = (f32x4){0.f, 0.f, 0.f, 0.f};

  // A fragment loads: coalesced 16B/lane from xf (L2-resident, 2 MB)
  auto loadA = [&](f16x8 ar[2][4], int kb) {
    const ushort* base = xf + ((size_t)kb * 4 + w) * 4096 + (size_t)l * 8;
#pragma unroll
    for (int mt = 0; mt < 4; ++mt)
#pragma unroll
      for (int ks2 = 0; ks2 < 2; ++ks2)
        ar[ks2][mt] = *(const f16x8*)(base + (mt * 2 + ks2) * 512);
  };

  auto loadQ = [&](int4 q[4], int s) {
#pragma unroll
    for (int p = 0; p < 4; ++p) q[p] = *(const int4*)(qbase[p] + (size_t)s * 64);
  };

  // dequant 16 codes of absolute k-block kbt -> target Bbuf
  auto dequantF = [&](int4 q[4], int kbt, ushort* bb) {
#pragma unroll
    for (int p = 0; p < 4; ++p) {
      int r = p * 16 + qrg;
      __half2 ax2 = __float2half2_rn(Qax[(kbt >> 2) * 256 + r * 4 + (kbt & 3)]);
      *(uint2*)&bb[bdst[p]] = dq4(q[p], ax2, tbits);
    }
  };

  auto compute = [&](f16x8 ar[2][4], const ushort* bb) {
    __builtin_amdgcn_s_setprio(1);
#pragma unroll
    for (int ks2 = 0; ks2 < 2; ++ks2) {
      f16x8 b[4];
#pragma unroll
      for (int nt = 0; nt < 4; ++nt) b[nt] = *(const f16x8*)&bb[boff[ks2][nt]];
#pragma unroll
      for (int mt = 0; mt < 4; ++mt)
#pragma unroll
        for (int nt = 0; nt < 4; ++nt)
          acc[mt][nt] = __builtin_amdgcn_mfma_f32_16x16x32_f16(ar[ks2][mt], b[nt], acc[mt][nt], 0, 0, 0);
    }
    __builtin_amdgcn_s_setprio(0);
  };

  // prologue: Qax full rows via DMA; A(0),A(1),q(0),q(1) into registers
  if (w == 0) {
#pragma unroll
    for (int j = 0; j < 16; ++j)
      async_cp16(am + (size_t)(n0 + l) * 64 + j * 4, (char*)Qax + j * 1024);
  }
  f16x8 arA[2][4], arB[2][4];
  int4 qA[4], qB[4];
  loadA(arA, kb0);
  loadA(arB, kb0 + 1);
  loadQ(qA, 0);
  loadQ(qB, 1);
  __syncthreads();  // drains Qax DMA (vmcnt+lgkm), once
  dequantF(qA, kb0, Bbuf[0]);
  step_barrier();

  // main loop: nst even; B(t) lives in Bbuf[t&1].
  // Phase order: loadQ FIRST (target regs are dead), then compute, then loadA
  // (regs consumed by compute), then dequant, then no-drain barrier.
  for (int s = 0; s < nst; s += 2) {
    // even phase
    if (s + 2 < nst) loadQ(qA, s + 2);
    compute(arA, Bbuf[0]);
    if (s + 2 < nst) loadA(arA, kb0 + s + 2);
    if (s + 1 < nst) dequantF(qB, kb0 + s + 1, Bbuf[1]);
    step_barrier();
    // odd phase
    if (s + 3 < nst) loadQ(qB, s + 3);
    compute(arB, Bbuf[1]);
    if (s + 3 < nst) loadA(arB, kb0 + s + 3);
    if (s + 2 < nst) dequantF(qA, kb0 + s + 2, Bbuf[0]);
    step_barrier();
  }

  if (split == 0) {
    // lora K-extension: k in [0,32) (rank 16 + zero pad); direct register frags
    f16x8 a_l[4], b_l[4];
#pragma unroll
    for (int mt = 0; mt < 4; ++mt)
      a_l[mt] = *(const f16x8*)(xa2 + (size_t)(w * 64 + mt * 16 + rlo) * 64 + chunk * 8);
#pragma unroll
    for (int nt = 0; nt < 4; ++nt)
      b_l[nt] = *(const f16x8*)(lBh + (size_t)(n0 + nt * 16 + rlo) * 64 + chunk * 8);
#pragma unroll
    for (int mt = 0; mt < 4; ++mt)
#pragma unroll
      for (int nt = 0; nt < 4; ++nt)
        acc[mt][nt] = __builtin_amdgcn_mfma_f32_16x16x32_f16(a_l[mt], b_l[nt], acc[mt][nt], 0, 0, 0);
  }

  // epilogue: C/D layout col=lane&15, row=(lane>>4)*4+reg; each split owns a slice
  if (fp16out) {
    ushort* dst = dest16 + (size_t)split * TOK * OUTF;
#pragma unroll
    for (int mt = 0; mt < 4; ++mt) {
#pragma unroll
      for (int nt = 0; nt < 4; ++nt) {
        int c = n0 + nt * 16 + rlo;
#pragma unroll
        for (int r = 0; r < 4; ++r) {
          int row = w * 64 + mt * 16 + chunk * 4 + r;
          dst[(size_t)row * OUTF + c] = f2h(acc[mt][nt][r]);
        }
      }
    }
  } else {
    float* dst = dest32;
#pragma unroll
    for (int mt = 0; mt < 4; ++mt) {
#pragma unroll
      for (int nt = 0; nt < 4; ++nt) {
        int c = n0 + nt * 16 + rlo;
#pragma unroll
        for (int r = 0; r < 4; ++r) {
          int row = w * 64 + mt * 16 + chunk * 4 + r;
          dst[(size_t)row * OUTF + c] = acc[mt][nt][r];
        }
      }
    }
  }
}

// kernel 3: sum f16 K-split partials -> f32 out; 8 halfs (uint4) per thread
__global__ void reduce_kernel(const uint4* __restrict__ part, float4* __restrict__ out,
                              int ks) {
  const int QN8 = TOK * OUTF / 8;
  int i = blockIdx.x * blockDim.x + threadIdx.x;
  if (i < QN8) {
    float s0 = 0.f, s1 = 0.f, s2 = 0.f, s3 = 0.f, s4 = 0.f, s5 = 0.f, s6 = 0.f, s7 = 0.f;
    for (int sp = 0; sp < ks; ++sp) {
      uint4 v = part[(size_t)sp * QN8 + i];
      union { uint u; __half2 h; } a, b, c, d;
      a.u = v.x; b.u = v.y; c.u = v.z; d.u = v.w;
      float2 fa = __half22float2(a.h), fb = __half22float2(b.h);
      float2 fc = __half22float2(c.h), fd = __half22float2(d.h);
      s0 += fa.x; s1 += fa.y; s2 += fb.x; s3 += fb.y;
      s4 += fc.x; s5 += fc.y; s6 += fd.x; s7 += fd.y;
    }
    out[2 * i] = (float4){s0, s1, s2, s3};
    out[2 * i + 1] = (float4){s4, s5, s6, s7};
  }
}

extern "C" void kernel_launch(void* const* d_in, const int* in_sizes, int n_in,
                              void* d_out, int out_size, void* d_ws, size_t ws_size,
                              hipStream_t stream) {
  const float* x = (const float*)d_in[0];
  const int* qc = (const int*)d_in[1];
  const float* am = (const float*)d_in[2];
  const float* lA = (const float*)d_in[3];
  const float* lB = (const float*)d_in[4];
  float* out = (float*)d_out;

  const size_t off_lB = (size_t)TOK * INF * 2;              // 2.10 MB (xf)
  const size_t off_xa2 = off_lB + (size_t)OUTF * 64 * 2;    // +1.41 MB
  const size_t off_part = off_xa2 + (size_t)TOK * 64 * 2;   // +32 KB
  const size_t part_bytes = (size_t)TOK * OUTF * 2;         // 5.63 MB per split (f16)

  ushort* xf = (ushort*)d_ws;
  ushort* lBh = (ushort*)((char*)d_ws + off_lB);
  ushort* xa2 = (ushort*)((char*)d_ws + off_xa2);
  ushort* part = (ushort*)((char*)d_ws + off_part);

  int ks = 1;
  if (ws_size >= off_part + 8 * part_bytes) ks = 8;       // ws ~688 MB observed -> ks=8
  else if (ws_size >= off_part + 4 * part_bytes) ks = 4;
  else if (ws_size >= off_part + 2 * part_bytes) ks = 2;
  const int fp16out = (ks > 1) ? 1 : 0;

  prep_kernel<<<512, 1024, 0, stream>>>(x, (uint4*)xf, (const float4*)lB,
                                        (ushort4*)lBh, lA, xa2);
  gemm_kernel<<<NT2 * ks, 256, 0, stream>>>(qc, am, xf, lBh, xa2, out, part,
                                            64 / ks, fp16out);
  if (ks > 1)
    reduce_kernel<<<(TOK * OUTF / 8 + 255) / 256, 256, 0, stream>>>((const uint4*)part,
                                                                    (float4*)out, ks);
}

// Round 6
// 359.530 us; speedup vs baseline: 1.4824x; 1.4824x over previous
//
#include <hip/hip_runtime.h>
#include <hip/hip_fp16.h>

typedef unsigned int uint;
typedef unsigned short ushort;

typedef __attribute__((ext_vector_type(8))) _Float16 f16x8;
typedef __attribute__((ext_vector_type(4))) float f32x4;

#define TOK 256
#define OUTF 11008
#define INF 4096
#define BM 256
#define BN 64
#define NT2 172     // OUTF / BN
#define NWT 11008   // 172 n-groups * 64 k-blocks

__device__ __constant__ float NF4_TBL[16] = {
    -1.0f, -0.6961928009986877f, -0.5250730514526367f, -0.39491748809814453f,
    -0.28444138169288635f, -0.18477343022823334f, -0.09105003625154495f, 0.0f,
    0.07958029955625534f, 0.16093020141124725f, 0.24611230194568634f,
    0.33791524171829224f, 0.44070982933044434f, 0.5626170039176941f,
    0.7229568362236023f, 1.0f};

__device__ __forceinline__ ushort f2h(float f) {
  return __half_as_ushort(__float2half(f));
}

// table value via VGPR crossbar (conflict-free); lanes 0..15 of every 16 hold the table
__device__ __forceinline__ float nf4v(int c, int tbits) {
  return __int_as_float(__builtin_amdgcn_ds_bpermute(c << 2, tbits));
}

// 4 raw codes -> 4 scaled halfs (8B)
__device__ __forceinline__ uint2 dq4(int4 c, __half2 ax2, int tbits) {
  __half2 h0 = __floats2half2_rn(nf4v(c.x, tbits), nf4v(c.y, tbits));
  __half2 h1 = __floats2half2_rn(nf4v(c.z, tbits), nf4v(c.w, tbits));
  h0 = __hmul2(h0, ax2);
  h1 = __hmul2(h1, ax2);
  union { __half2 h[2]; uint2 u; } r;
  r.h[0] = h0; r.h[1] = h1;
  return r.u;
}

// kernel 1: blocks [0,NWT): FULL DEQUANT of one (n-group g, k-block kb) tile:
//   read 64 rows x 64 codes (16 KB int32, coalesced 64B/lane), dequant via
//   bpermute, write 8 KB f16 in gemm B-FRAGMENT order:
//   uint4 index within tile = cons_lane*8 + frag, cons_lane = chunk*16+rlo,
//   frag = ks2*4+nt, for W row r = nt*16+rlo, cols (ks2*4+chunk)*8..+8.
// blocks [NWT, NWT+256): x fp32 -> f16 fragment layout xf; lora_B -> f16 padded.
__global__ __launch_bounds__(256)
void prep_kernel(const int* __restrict__ qc, const float* __restrict__ am,
                 uint4* __restrict__ wf4, const float* __restrict__ x,
                 uint4* __restrict__ xf4, const float4* __restrict__ lB4,
                 ushort4* __restrict__ lBh4) {
  const int tid = threadIdx.x;
  if (blockIdx.x < NWT) {
    const int b = blockIdx.x;        // = g*64 + kb
    const int g = b >> 6, kb = b & 63;
    const int r = tid >> 2;          // 0..63: row within n-group
    const int c = tid & 3;           // 0..3: 16-code chunk within k-block
    const int n = g * 64 + r;
    const int tbits = __float_as_int(NF4_TBL[tid & 15]);
    const __half2 ax2 = __float2half2_rn(am[(size_t)n * 64 + kb]);
    const int4* src = (const int4*)(qc + (size_t)n * INF + kb * 64 + c * 16);
    int4 q0 = src[0], q1 = src[1], q2 = src[2], q3 = src[3];
    uint2 d0 = dq4(q0, ax2, tbits), d1 = dq4(q1, ax2, tbits);
    uint2 d2 = dq4(q2, ax2, tbits), d3 = dq4(q3, ax2, tbits);
    const int rlo = r & 15, nt = r >> 4;
    const int i8a = c * 2, i8b = c * 2 + 1;  // 8-code column groups
    uint4* dst = wf4 + (size_t)b * 512;      // 512 uint4 = 8 KB per tile
    dst[((i8a & 3) * 16 + rlo) * 8 + (i8a >> 2) * 4 + nt] = (uint4){d0.x, d0.y, d1.x, d1.y};
    dst[((i8b & 3) * 16 + rlo) * 8 + (i8b >> 2) * 4 + nt] = (uint4){d2.x, d2.y, d3.x, d3.y};
  } else {
    const int stride = 256 * 256;
    const int t0 = (blockIdx.x - NWT) * 256 + tid;
    // x -> fragment layout: one 16B frag per iteration (8 halfs along k of one row)
    for (int f = t0; f < TOK * INF / 8; f += stride) {
      int l = f & 63;
      int rlo = l & 15, chunk = l >> 4;
      int ms = (f >> 6) & 7;      // mt*2 + ks2
      int mt = ms >> 1, ks2 = ms & 1;
      int w = (f >> 9) & 3;
      int kb = f >> 11;
      int m = w * 64 + mt * 16 + rlo;
      int k0 = kb * 64 + (ks2 * 4 + chunk) * 8;
      const float4* src = (const float4*)(x + (size_t)m * INF + k0);
      float4 v0 = src[0], v1 = src[1];
      union { ushort4 h[2]; uint4 u; } pk;
      pk.h[0].x = f2h(v0.x); pk.h[0].y = f2h(v0.y); pk.h[0].z = f2h(v0.z); pk.h[0].w = f2h(v0.w);
      pk.h[1].x = f2h(v1.x); pk.h[1].y = f2h(v1.y); pk.h[1].z = f2h(v1.z); pk.h[1].w = f2h(v1.w);
      xf4[f] = pk.u;
    }
    for (int i = t0; i < OUTF * 16; i += stride) {
      int n = i >> 4, jq = i & 15;
      ushort4 o = {0, 0, 0, 0};
      if (jq < 4) {
        float4 v = lB4[n * 4 + jq];
        o.x = f2h(v.x); o.y = f2h(v.y); o.z = f2h(v.z); o.w = f2h(v.w);
      }
      lBh4[i] = o;
    }
  }
}

// kernel 2: xa2[m][j] = f16( 2 * sum_k x[m][k]*lora_A[j][k] ), [TOK,64] zero-padded
__global__ __launch_bounds__(1024)
void xa_kernel(const float* __restrict__ x, const float* __restrict__ lA,
               ushort* __restrict__ xa2) {
  const int m = blockIdx.x;
  const int t = threadIdx.x;
  const float4* x4 = (const float4*)(x + (size_t)m * INF);
  const float4* lA4 = (const float4*)lA;
  float4 xv = x4[t];
  float acc[16];
#pragma unroll
  for (int j = 0; j < 16; ++j) {
    float4 a = lA4[j * (INF / 4) + t];
    acc[j] = xv.x * a.x + xv.y * a.y + xv.z * a.z + xv.w * a.w;
  }
#pragma unroll
  for (int j = 0; j < 16; ++j)
#pragma unroll
    for (int s = 32; s > 0; s >>= 1) acc[j] += __shfl_xor(acc[j], s, 64);
  __shared__ float red[16][16];
  const int w = t >> 6, l = t & 63;
  if (l == 0) {
#pragma unroll
    for (int j = 0; j < 16; ++j) red[w][j] = acc[j];
  }
  __syncthreads();
  if (t < 64) {
    ushort v = 0;
    if (t < 16) {
      float s = 0.f;
#pragma unroll
      for (int w2 = 0; w2 < 16; ++w2) s += red[w2][t];
      v = f2h(2.0f * s);
    }
    xa2[m * 64 + t] = v;
  }
}

// kernel 3: pure f16 GEMM — ZERO LDS, ZERO barriers. A and B fragments are
// direct coalesced 128B/lane register loads (pre-fragmented by prep),
// double-buffered; compiler inserts counted vmcnt. Waves fully independent.
__global__ __launch_bounds__(256, 2)
void gemm_kernel(const ushort* __restrict__ wf, const ushort* __restrict__ xf,
                 const ushort* __restrict__ lBh, const ushort* __restrict__ xa2,
                 float* __restrict__ dest32, ushort* __restrict__ dest16,
                 int nst, int fp16out) {
  const int tid = threadIdx.x;
  const int w = tid >> 6;
  const int l = tid & 63;
  const int chunk = l >> 4;  // 0..3
  const int rlo = l & 15;
  const int split = blockIdx.x / NT2;
  const int ntile = blockIdx.x - split * NT2;
  const int n0 = ntile * BN;
  const int kb0 = split * nst;  // in 64-k blocks

  f32x4 acc[4][4];
#pragma unroll
  for (int mt = 0; mt < 4; ++mt)
#pragma unroll
    for (int nt = 0; nt < 4; ++nt) acc[mt][nt] = (f32x4){0.f, 0.f, 0.f, 0.f};

  // A frags: 8 x 16B from xf (L2-resident 2 MB); index i = mt*2+ks2
  auto loadA = [&](f16x8 ar[8], int kb) {
    const ushort* base = xf + ((size_t)kb * 4 + w) * 4096 + l * 8;
#pragma unroll
    for (int i = 0; i < 8; ++i) ar[i] = *(const f16x8*)(base + i * 512);
  };
  // B frags: 8 x 16B contiguous 128B/lane from wf (fragment-ordered by prep);
  // index f = ks2*4+nt. All 4 waves read identical 8 KB -> L1-served x3.
  auto loadB = [&](f16x8 br[8], int kb) {
    const ushort* base = wf + (size_t)(ntile * 64 + kb) * 4096 + l * 64;
#pragma unroll
    for (int f = 0; f < 8; ++f) br[f] = *(const f16x8*)(base + f * 8);
  };
  auto compute = [&](f16x8 ar[8], f16x8 br[8]) {
    __builtin_amdgcn_s_setprio(1);
#pragma unroll
    for (int ks2 = 0; ks2 < 2; ++ks2)
#pragma unroll
      for (int mt = 0; mt < 4; ++mt)
#pragma unroll
        for (int nt = 0; nt < 4; ++nt)
          acc[mt][nt] = __builtin_amdgcn_mfma_f32_16x16x32_f16(
              ar[mt * 2 + ks2], br[ks2 * 4 + nt], acc[mt][nt], 0, 0, 0);
    __builtin_amdgcn_s_setprio(0);
  };

  f16x8 aA[8], bA[8], aB[8], bB[8];
  loadB(bA, kb0);
  loadA(aA, kb0);
  loadB(bB, kb0 + 1);
  loadA(aB, kb0 + 1);

  for (int s = 0; s < nst; s += 2) {
    compute(aA, bA);
    if (s + 2 < nst) { loadB(bA, kb0 + s + 2); loadA(aA, kb0 + s + 2); }
    compute(aB, bB);
    if (s + 3 < nst) { loadB(bB, kb0 + s + 3); loadA(aB, kb0 + s + 3); }
  }

  if (split == 0) {
    // lora K-extension: k in [0,32) (rank 16 + zero pad); direct register frags
    f16x8 a_l[4], b_l[4];
#pragma unroll
    for (int mt = 0; mt < 4; ++mt)
      a_l[mt] = *(const f16x8*)(xa2 + (size_t)(w * 64 + mt * 16 + rlo) * 64 + chunk * 8);
#pragma unroll
    for (int nt = 0; nt < 4; ++nt)
      b_l[nt] = *(const f16x8*)(lBh + (size_t)(n0 + nt * 16 + rlo) * 64 + chunk * 8);
#pragma unroll
    for (int mt = 0; mt < 4; ++mt)
#pragma unroll
      for (int nt = 0; nt < 4; ++nt)
        acc[mt][nt] = __builtin_amdgcn_mfma_f32_16x16x32_f16(a_l[mt], b_l[nt], acc[mt][nt], 0, 0, 0);
  }

  // epilogue: C/D layout col=lane&15, row=(lane>>4)*4+reg; each split owns a slice
  if (fp16out) {
    ushort* dst = dest16 + (size_t)split * TOK * OUTF;
#pragma unroll
    for (int mt = 0; mt < 4; ++mt) {
#pragma unroll
      for (int nt = 0; nt < 4; ++nt) {
        int c = n0 + nt * 16 + rlo;
#pragma unroll
        for (int r = 0; r < 4; ++r) {
          int row = w * 64 + mt * 16 + chunk * 4 + r;
          dst[(size_t)row * OUTF + c] = f2h(acc[mt][nt][r]);
        }
      }
    }
  } else {
    float* dst = dest32;
#pragma unroll
    for (int mt = 0; mt < 4; ++mt) {
#pragma unroll
      for (int nt = 0; nt < 4; ++nt) {
        int c = n0 + nt * 16 + rlo;
#pragma unroll
        for (int r = 0; r < 4; ++r) {
          int row = w * 64 + mt * 16 + chunk * 4 + r;
          dst[(size_t)row * OUTF + c] = acc[mt][nt][r];
        }
      }
    }
  }
}

// kernel 4: sum f16 K-split partials -> f32 out; 8 halfs (uint4) per thread
__global__ void reduce_kernel(const uint4* __restrict__ part, float4* __restrict__ out,
                              int ks) {
  const int QN8 = TOK * OUTF / 8;
  int i = blockIdx.x * blockDim.x + threadIdx.x;
  if (i < QN8) {
    float s0 = 0.f, s1 = 0.f, s2 = 0.f, s3 = 0.f, s4 = 0.f, s5 = 0.f, s6 = 0.f, s7 = 0.f;
    for (int sp = 0; sp < ks; ++sp) {
      uint4 v = part[(size_t)sp * QN8 + i];
      union { uint u; __half2 h; } a, b, c, d;
      a.u = v.x; b.u = v.y; c.u = v.z; d.u = v.w;
      float2 fa = __half22float2(a.h), fb = __half22float2(b.h);
      float2 fc = __half22float2(c.h), fd = __half22float2(d.h);
      s0 += fa.x; s1 += fa.y; s2 += fb.x; s3 += fb.y;
      s4 += fc.x; s5 += fc.y; s6 += fd.x; s7 += fd.y;
    }
    out[2 * i] = (float4){s0, s1, s2, s3};
    out[2 * i + 1] = (float4){s4, s5, s6, s7};
  }
}

extern "C" void kernel_launch(void* const* d_in, const int* in_sizes, int n_in,
                              void* d_out, int out_size, void* d_ws, size_t ws_size,
                              hipStream_t stream) {
  const float* x = (const float*)d_in[0];
  const int* qc = (const int*)d_in[1];
  const float* am = (const float*)d_in[2];
  const float* lA = (const float*)d_in[3];
  const float* lB = (const float*)d_in[4];
  float* out = (float*)d_out;

  const size_t off_lB = (size_t)TOK * INF * 2;              // 2.10 MB (xf)
  const size_t off_xa2 = off_lB + (size_t)OUTF * 64 * 2;    // +1.41 MB
  const size_t off_wf = off_xa2 + (size_t)TOK * 64 * 2;     // +32 KB
  const size_t off_part = off_wf + (size_t)NWT * 8192;      // +90.2 MB (wf)
  const size_t part_bytes = (size_t)TOK * OUTF * 2;         // 5.63 MB per split (f16)

  ushort* xf = (ushort*)d_ws;
  ushort* lBh = (ushort*)((char*)d_ws + off_lB);
  ushort* xa2 = (ushort*)((char*)d_ws + off_xa2);
  ushort* wf = (ushort*)((char*)d_ws + off_wf);
  ushort* part = (ushort*)((char*)d_ws + off_part);

  int ks = 1;
  if (ws_size >= off_part + 8 * part_bytes) ks = 8;       // ws ~688 MB observed -> ks=8
  else if (ws_size >= off_part + 4 * part_bytes) ks = 4;
  else if (ws_size >= off_part + 2 * part_bytes) ks = 2;
  const int fp16out = (ks > 1) ? 1 : 0;

  prep_kernel<<<NWT + 256, 256, 0, stream>>>(qc, am, (uint4*)wf, x, (uint4*)xf,
                                             (const float4*)lB, (ushort4*)lBh);
  xa_kernel<<<TOK, 1024, 0, stream>>>(x, lA, xa2);
  gemm_kernel<<<NT2 * ks, 256, 0, stream>>>(wf, xf, lBh, xa2, out, part,
                                            64 / ks, fp16out);
  if (ks > 1)
    reduce_kernel<<<(TOK * OUTF / 8 + 255) / 256, 256, 0, stream>>>((const uint4*)part,
                                                                    (float4*)out, ks);
}

// Round 7
// 336.347 us; speedup vs baseline: 1.5846x; 1.0689x over previous
//
#include <hip/hip_runtime.h>
#include <hip/hip_fp16.h>

typedef unsigned int uint;
typedef unsigned short ushort;

typedef __attribute__((ext_vector_type(8))) _Float16 f16x8;
typedef __attribute__((ext_vector_type(4))) float f32x4;

#define TOK 256
#define OUTF 11008
#define INF 4096
#define BN 64
#define NT2 172  // OUTF / BN

__device__ __constant__ float NF4_TBL[16] = {
    -1.0f, -0.6961928009986877f, -0.5250730514526367f, -0.39491748809814453f,
    -0.28444138169288635f, -0.18477343022823334f, -0.09105003625154495f, 0.0f,
    0.07958029955625534f, 0.16093020141124725f, 0.24611230194568634f,
    0.33791524171829224f, 0.44070982933044434f, 0.5626170039176941f,
    0.7229568362236023f, 1.0f};

__device__ __forceinline__ ushort f2h(float f) {
  return __half_as_ushort(__float2half(f));
}

// table value via VGPR crossbar (conflict-free); lanes 0..15 of every 16 hold the table
__device__ __forceinline__ float nf4v(int c, int tbits) {
  return __int_as_float(__builtin_amdgcn_ds_bpermute(c << 2, tbits));
}

// 4 raw codes -> 4 scaled halfs (8B)
__device__ __forceinline__ uint2 dq4(int4 c, __half2 ax2, int tbits) {
  __half2 h0 = __floats2half2_rn(nf4v(c.x, tbits), nf4v(c.y, tbits));
  __half2 h1 = __floats2half2_rn(nf4v(c.z, tbits), nf4v(c.w, tbits));
  h0 = __hmul2(h0, ax2);
  h1 = __hmul2(h1, ax2);
  union { __half2 h[2]; uint2 u; } r;
  r.h[0] = h0; r.h[1] = h1;
  return r.u;
}

// kernel 1: x fp32 -> f16 in MFMA-fragment layout xf
// (16B frag f = ((kb*4 + m64)*8 + (mt*2+ks2))*64 + lane, m = m64*64+mt*16+rlo,
//  k = kb*64 + (ks2*4+chunk)*8); lora_B fp32 [OUTF,16] -> f16 [OUTF,64] padded.
__global__ void prep_kernel(const float* __restrict__ x, uint4* __restrict__ xf4,
                            const float4* __restrict__ lB4, ushort4* __restrict__ lBh4) {
  const int stride = gridDim.x * blockDim.x;
  const int t0 = blockIdx.x * blockDim.x + threadIdx.x;
  for (int f = t0; f < TOK * INF / 8; f += stride) {
    int l = f & 63;
    int rlo = l & 15, chunk = l >> 4;
    int ms = (f >> 6) & 7;      // mt*2 + ks2
    int mt = ms >> 1, ks2 = ms & 1;
    int m64 = (f >> 9) & 3;
    int kb = f >> 11;
    int m = m64 * 64 + mt * 16 + rlo;
    int k0 = kb * 64 + (ks2 * 4 + chunk) * 8;
    const float4* src = (const float4*)(x + (size_t)m * INF + k0);
    float4 v0 = src[0], v1 = src[1];
    union { ushort4 h[2]; uint4 u; } pk;
    pk.h[0].x = f2h(v0.x); pk.h[0].y = f2h(v0.y); pk.h[0].z = f2h(v0.z); pk.h[0].w = f2h(v0.w);
    pk.h[1].x = f2h(v1.x); pk.h[1].y = f2h(v1.y); pk.h[1].z = f2h(v1.z); pk.h[1].w = f2h(v1.w);
    xf4[f] = pk.u;
  }
  for (int i = t0; i < OUTF * 16; i += stride) {
    int n = i >> 4, jq = i & 15;
    ushort4 o = {0, 0, 0, 0};
    if (jq < 4) {
      float4 v = lB4[n * 4 + jq];
      o.x = f2h(v.x); o.y = f2h(v.y); o.z = f2h(v.z); o.w = f2h(v.w);
    }
    lBh4[i] = o;
  }
}

// kernel 2: xa2[m][j] = f16( 2 * sum_k x[m][k]*lora_A[j][k] ), [TOK,64] zero-padded
__global__ __launch_bounds__(1024)
void xa_kernel(const float* __restrict__ x, const float* __restrict__ lA,
               ushort* __restrict__ xa2) {
  const int m = blockIdx.x;
  const int t = threadIdx.x;
  const float4* x4 = (const float4*)(x + (size_t)m * INF);
  const float4* lA4 = (const float4*)lA;
  float4 xv = x4[t];
  float acc[16];
#pragma unroll
  for (int j = 0; j < 16; ++j) {
    float4 a = lA4[j * (INF / 4) + t];
    acc[j] = xv.x * a.x + xv.y * a.y + xv.z * a.z + xv.w * a.w;
  }
#pragma unroll
  for (int j = 0; j < 16; ++j)
#pragma unroll
    for (int s = 32; s > 0; s >>= 1) acc[j] += __shfl_xor(acc[j], s, 64);
  __shared__ float red[16][16];
  const int w = t >> 6, l = t & 63;
  if (l == 0) {
#pragma unroll
    for (int j = 0; j < 16; ++j) red[w][j] = acc[j];
  }
  __syncthreads();
  if (t < 64) {
    ushort v = 0;
    if (t < 16) {
      float s = 0.f;
#pragma unroll
      for (int w2 = 0; w2 < 16; ++w2) s += red[w2][t];
      v = f2h(2.0f * s);
    }
    xa2[m * 64 + t] = v;
  }
}

// kernel 3: fused dequant GEMM — ZERO LDS, ZERO barriers, waves independent.
// Wave w of block (ntile,split): output cols nw0=ntile*64+w*16 .. +16, ALL 256
// rows, k-blocks kb0..kb0+nst. Lane (chunk,rlo) serves W row nw0+rlo and cols
// (ks2*4+chunk)*8..+8 of each k-block: it LOADS exactly its own B-fragment's
// 16 raw codes (2x int4 per ks2; 4 chunk-lanes/row coalesce to 128B lines),
// dequants in-register via bpermute (no redistribution needed), and feeds
// 32 MFMAs/k-block over acc[16]. Codes+absmax double-buffered (named regs),
// A-frags stream from L2-resident xf inside the unrolled sweep.
__global__ __launch_bounds__(256, 2)
void gemm_kernel(const int* __restrict__ qc, const float* __restrict__ am,
                 const ushort* __restrict__ xf, const ushort* __restrict__ lBh,
                 const ushort* __restrict__ xa2, float* __restrict__ dest32,
                 ushort* __restrict__ dest16, int nst, int fp16out) {
  const int tid = threadIdx.x;
  const int w = tid >> 6;
  const int l = tid & 63;
  const int chunk = l >> 4;  // 0..3
  const int rlo = l & 15;
  const int split = blockIdx.x / NT2;
  const int ntile = blockIdx.x - split * NT2;
  const int nw0 = ntile * BN + w * 16;
  const int kb0 = split * nst;  // in 64-k blocks
  const int nr = nw0 + rlo;     // W row / output col this lane serves

  const int tbits = __float_as_int(NF4_TBL[l & 15]);
  const int* qrow = qc + (size_t)nr * INF + chunk * 8;
  const float* arow = am + (size_t)nr * 64;

  f32x4 acc[16];
#pragma unroll
  for (int mt = 0; mt < 16; ++mt) acc[mt] = (f32x4){0.f, 0.f, 0.f, 0.f};

  // codes for one k-block: ks2=0 -> c[0],c[1] (cols chunk*8..+8);
  // ks2=1 -> c[2],c[3] (cols 32+chunk*8..+8)
  auto loadC = [&](int4 (&c)[4], float& ax, int kb) {
    const int* p = qrow + kb * 64;
    c[0] = *(const int4*)(p);
    c[1] = *(const int4*)(p + 4);
    c[2] = *(const int4*)(p + 32);
    c[3] = *(const int4*)(p + 36);
    ax = arow[kb];
  };
  auto dqB = [&](const int4 (&c)[4], float ax, f16x8& b0, f16x8& b1) {
    __half2 ax2 = __float2half2_rn(ax);
    union { uint2 u2[2]; f16x8 f; } u0, u1;
    u0.u2[0] = dq4(c[0], ax2, tbits);
    u0.u2[1] = dq4(c[1], ax2, tbits);
    u1.u2[0] = dq4(c[2], ax2, tbits);
    u1.u2[1] = dq4(c[3], ax2, tbits);
    b0 = u0.f; b1 = u1.f;
  };
  // 16 M-frags x 2 ks2: A streamed from xf, 32 MFMAs
  auto sweep = [&](int kb, f16x8 b0, f16x8 b1) {
    __builtin_amdgcn_s_setprio(1);
#pragma unroll
    for (int mt = 0; mt < 16; ++mt) {
      const ushort* base =
          xf + (((size_t)kb * 4 + (mt >> 2)) * 8 + (mt & 3) * 2) * 512 + l * 8;
      f16x8 a0 = *(const f16x8*)(base);
      f16x8 a1 = *(const f16x8*)(base + 512);
      acc[mt] = __builtin_amdgcn_mfma_f32_16x16x32_f16(a0, b0, acc[mt], 0, 0, 0);
      acc[mt] = __builtin_amdgcn_mfma_f32_16x16x32_f16(a1, b1, acc[mt], 0, 0, 0);
    }
    __builtin_amdgcn_s_setprio(0);
  };

  int4 cA[4], cB[4];
  float axA, axB;
  loadC(cA, axA, kb0);
  if (nst > 1) loadC(cB, axB, kb0 + 1);

  for (int s = 0; s < nst; s += 2) {
    f16x8 b0, b1;
    dqB(cA, axA, b0, b1);
    if (s + 2 < nst) loadC(cA, axA, kb0 + s + 2);
    sweep(kb0 + s, b0, b1);
    if (s + 1 < nst) {
      f16x8 b2, b3;
      dqB(cB, axB, b2, b3);
      if (s + 3 < nst) loadC(cB, axB, kb0 + s + 3);
      sweep(kb0 + s + 1, b2, b3);
    }
  }

  if (split == 0) {
    // lora K-extension: k in [0,32) (rank 16 + zero pad); one B-frag per wave
    f16x8 b_l = *(const f16x8*)(lBh + (size_t)nr * 64 + chunk * 8);
#pragma unroll
    for (int mt = 0; mt < 16; ++mt) {
      f16x8 a_l = *(const f16x8*)(xa2 + (size_t)(mt * 16 + rlo) * 64 + chunk * 8);
      acc[mt] = __builtin_amdgcn_mfma_f32_16x16x32_f16(a_l, b_l, acc[mt], 0, 0, 0);
    }
  }

  // epilogue: C/D layout col=lane&15 -> nr, row = mt*16 + chunk*4 + r
  if (fp16out) {
    ushort* dst = dest16 + (size_t)split * TOK * OUTF + nr;
#pragma unroll
    for (int mt = 0; mt < 16; ++mt)
#pragma unroll
      for (int r = 0; r < 4; ++r)
        dst[(size_t)(mt * 16 + chunk * 4 + r) * OUTF] = f2h(acc[mt][r]);
  } else {
    float* dst = dest32 + nr;
#pragma unroll
    for (int mt = 0; mt < 16; ++mt)
#pragma unroll
      for (int r = 0; r < 4; ++r)
        dst[(size_t)(mt * 16 + chunk * 4 + r) * OUTF] = acc[mt][r];
  }
}

// kernel 4: sum f16 K-split partials -> f32 out; 8 halfs (uint4) per thread
__global__ void reduce_kernel(const uint4* __restrict__ part, float4* __restrict__ out,
                              int ks) {
  const int QN8 = TOK * OUTF / 8;
  int i = blockIdx.x * blockDim.x + threadIdx.x;
  if (i < QN8) {
    float s0 = 0.f, s1 = 0.f, s2 = 0.f, s3 = 0.f, s4 = 0.f, s5 = 0.f, s6 = 0.f, s7 = 0.f;
    for (int sp = 0; sp < ks; ++sp) {
      uint4 v = part[(size_t)sp * QN8 + i];
      union { uint u; __half2 h; } a, b, c, d;
      a.u = v.x; b.u = v.y; c.u = v.z; d.u = v.w;
      float2 fa = __half22float2(a.h), fb = __half22float2(b.h);
      float2 fc = __half22float2(c.h), fd = __half22float2(d.h);
      s0 += fa.x; s1 += fa.y; s2 += fb.x; s3 += fb.y;
      s4 += fc.x; s5 += fc.y; s6 += fd.x; s7 += fd.y;
    }
    out[2 * i] = (float4){s0, s1, s2, s3};
    out[2 * i + 1] = (float4){s4, s5, s6, s7};
  }
}

extern "C" void kernel_launch(void* const* d_in, const int* in_sizes, int n_in,
                              void* d_out, int out_size, void* d_ws, size_t ws_size,
                              hipStream_t stream) {
  const float* x = (const float*)d_in[0];
  const int* qc = (const int*)d_in[1];
  const float* am = (const float*)d_in[2];
  const float* lA = (const float*)d_in[3];
  const float* lB = (const float*)d_in[4];
  float* out = (float*)d_out;

  const size_t off_lB = (size_t)TOK * INF * 2;              // 2.10 MB (xf)
  const size_t off_xa2 = off_lB + (size_t)OUTF * 64 * 2;    // +1.41 MB
  const size_t off_part = off_xa2 + (size_t)TOK * 64 * 2;   // +32 KB
  const size_t part_bytes = (size_t)TOK * OUTF * 2;         // 5.63 MB per split (f16)

  ushort* xf = (ushort*)d_ws;
  ushort* lBh = (ushort*)((char*)d_ws + off_lB);
  ushort* xa2 = (ushort*)((char*)d_ws + off_xa2);
  ushort* part = (ushort*)((char*)d_ws + off_part);

  int ks = 1;
  if (ws_size >= off_part + 8 * part_bytes) ks = 8;       // ws ~688 MB -> ks=8
  else if (ws_size >= off_part + 4 * part_bytes) ks = 4;
  else if (ws_size >= off_part + 2 * part_bytes) ks = 2;
  const int fp16out = (ks > 1) ? 1 : 0;

  prep_kernel<<<2048, 256, 0, stream>>>(x, (uint4*)xf, (const float4*)lB,
                                        (ushort4*)lBh);
  xa_kernel<<<TOK, 1024, 0, stream>>>(x, lA, xa2);
  gemm_kernel<<<NT2 * ks, 256, 0, stream>>>(qc, am, xf, lBh, xa2, out, part,
                                            64 / ks, fp16out);
  if (ks > 1)
    reduce_kernel<<<(TOK * OUTF / 8 + 255) / 256, 256, 0, stream>>>((const uint4*)part,
                                                                    (float4*)out, ks);
}

// Round 8
// 335.881 us; speedup vs baseline: 1.5868x; 1.0014x over previous
//
#include <hip/hip_runtime.h>
#include <hip/hip_fp16.h>

typedef unsigned int uint;
typedef unsigned short ushort;

typedef __attribute__((ext_vector_type(8))) _Float16 f16x8;
typedef __attribute__((ext_vector_type(4))) float f32x4;

#define TOK 256
#define OUTF 11008
#define INF 4096
#define BN 64
#define NT2 172  // OUTF / BN

__device__ __constant__ float NF4_TBL[16] = {
    -1.0f, -0.6961928009986877f, -0.5250730514526367f, -0.39491748809814453f,
    -0.28444138169288635f, -0.18477343022823334f, -0.09105003625154495f, 0.0f,
    0.07958029955625534f, 0.16093020141124725f, 0.24611230194568634f,
    0.33791524171829224f, 0.44070982933044434f, 0.5626170039176941f,
    0.7229568362236023f, 1.0f};

__device__ __forceinline__ ushort f2h(float f) {
  return __half_as_ushort(__float2half(f));
}

// table value via VGPR crossbar (conflict-free); lanes 0..15 of every 16 hold the table
__device__ __forceinline__ float nf4v(int c, int tbits) {
  return __int_as_float(__builtin_amdgcn_ds_bpermute(c << 2, tbits));
}

// 4 raw codes -> 4 scaled halfs (8B)
__device__ __forceinline__ uint2 dq4(int4 c, __half2 ax2, int tbits) {
  __half2 h0 = __floats2half2_rn(nf4v(c.x, tbits), nf4v(c.y, tbits));
  __half2 h1 = __floats2half2_rn(nf4v(c.z, tbits), nf4v(c.w, tbits));
  h0 = __hmul2(h0, ax2);
  h1 = __hmul2(h1, ax2);
  union { __half2 h[2]; uint2 u; } r;
  r.h[0] = h0; r.h[1] = h1;
  return r.u;
}

// kernel 1: x fp32 -> f16 in MFMA-fragment layout xf
// (16B frag f = ((kb*4 + m64)*8 + (mt*2+ks2))*64 + lane, m = m64*64+mt*16+rlo,
//  k = kb*64 + (ks2*4+chunk)*8); lora_B fp32 [OUTF,16] -> f16 [OUTF,64] padded.
__global__ void prep_kernel(const float* __restrict__ x, uint4* __restrict__ xf4,
                            const float4* __restrict__ lB4, ushort4* __restrict__ lBh4) {
  const int stride = gridDim.x * blockDim.x;
  const int t0 = blockIdx.x * blockDim.x + threadIdx.x;
  for (int f = t0; f < TOK * INF / 8; f += stride) {
    int l = f & 63;
    int rlo = l & 15, chunk = l >> 4;
    int ms = (f >> 6) & 7;      // mt*2 + ks2
    int mt = ms >> 1, ks2 = ms & 1;
    int m64 = (f >> 9) & 3;
    int kb = f >> 11;
    int m = m64 * 64 + mt * 16 + rlo;
    int k0 = kb * 64 + (ks2 * 4 + chunk) * 8;
    const float4* src = (const float4*)(x + (size_t)m * INF + k0);
    float4 v0 = src[0], v1 = src[1];
    union { ushort4 h[2]; uint4 u; } pk;
    pk.h[0].x = f2h(v0.x); pk.h[0].y = f2h(v0.y); pk.h[0].z = f2h(v0.z); pk.h[0].w = f2h(v0.w);
    pk.h[1].x = f2h(v1.x); pk.h[1].y = f2h(v1.y); pk.h[1].z = f2h(v1.z); pk.h[1].w = f2h(v1.w);
    xf4[f] = pk.u;
  }
  for (int i = t0; i < OUTF * 16; i += stride) {
    int n = i >> 4, jq = i & 15;
    ushort4 o = {0, 0, 0, 0};
    if (jq < 4) {
      float4 v = lB4[n * 4 + jq];
      o.x = f2h(v.x); o.y = f2h(v.y); o.z = f2h(v.z); o.w = f2h(v.w);
    }
    lBh4[i] = o;
  }
}

// kernel 2: xa2[m][j] = f16( 2 * sum_k x[m][k]*lora_A[j][k] ), [TOK,64] zero-padded
__global__ __launch_bounds__(1024)
void xa_kernel(const float* __restrict__ x, const float* __restrict__ lA,
               ushort* __restrict__ xa2) {
  const int m = blockIdx.x;
  const int t = threadIdx.x;
  const float4* x4 = (const float4*)(x + (size_t)m * INF);
  const float4* lA4 = (const float4*)lA;
  float4 xv = x4[t];
  float acc[16];
#pragma unroll
  for (int j = 0; j < 16; ++j) {
    float4 a = lA4[j * (INF / 4) + t];
    acc[j] = xv.x * a.x + xv.y * a.y + xv.z * a.z + xv.w * a.w;
  }
#pragma unroll
  for (int j = 0; j < 16; ++j)
#pragma unroll
    for (int s = 32; s > 0; s >>= 1) acc[j] += __shfl_xor(acc[j], s, 64);
  __shared__ float red[16][16];
  const int w = t >> 6, l = t & 63;
  if (l == 0) {
#pragma unroll
    for (int j = 0; j < 16; ++j) red[w][j] = acc[j];
  }
  __syncthreads();
  if (t < 64) {
    ushort v = 0;
    if (t < 16) {
      float s = 0.f;
#pragma unroll
      for (int w2 = 0; w2 < 16; ++w2) s += red[w2][t];
      v = f2h(2.0f * s);
    }
    xa2[m * 64 + t] = v;
  }
}

// kernel 3: fused dequant GEMM — ZERO LDS, ZERO barriers, waves independent.
// Waves split the 256x64 block tile 2Mx2N: wave (wm,wn) owns rows wm*128..+128,
// cols nw0=ntile*64+wn*32..+32. Per k-block, each lane loads the raw codes of
// its OWN two B-fragments (8 int4, depth-2 register dbuf), and the k-block
// schedule is: BATCH-issue all 16 A-frags -> dequant (VALU/bpermute covers the
// L2 latency) -> single implicit vmcnt wait -> 32 MFMAs from registers.
// This replaces R7's 16 load-use stalls per k-block with ~1.
__global__ __launch_bounds__(256, 2)
void gemm_kernel(const int* __restrict__ qc, const float* __restrict__ am,
                 const ushort* __restrict__ xf, const ushort* __restrict__ lBh,
                 const ushort* __restrict__ xa2, float* __restrict__ dest32,
                 ushort* __restrict__ dest16, int nst, int fp16out) {
  const int tid = threadIdx.x;
  const int w = tid >> 6;
  const int wm = w >> 1;     // 0..1: M half
  const int wn = w & 1;      // 0..1: N half
  const int l = tid & 63;
  const int chunk = l >> 4;  // 0..3
  const int rlo = l & 15;
  const int split = blockIdx.x / NT2;
  const int ntile = blockIdx.x - split * NT2;
  const int nw0 = ntile * BN + wn * 32;
  const int kb0 = split * nst;  // in 64-k blocks

  const int tbits = __float_as_int(NF4_TBL[l & 15]);
  const int* qrow0 = qc + (size_t)(nw0 + rlo) * INF + chunk * 8;
  const int* qrow1 = qc + (size_t)(nw0 + 16 + rlo) * INF + chunk * 8;
  const float* arow0 = am + (size_t)(nw0 + rlo) * 64;
  const float* arow1 = am + (size_t)(nw0 + 16 + rlo) * 64;

  f32x4 acc[8][2];
#pragma unroll
  for (int mt = 0; mt < 8; ++mt)
#pragma unroll
    for (int nt = 0; nt < 2; ++nt) acc[mt][nt] = (f32x4){0.f, 0.f, 0.f, 0.f};

  // codes for one k-block: c[nt*4 + ks2*2 + {0,1}], 8 int4/lane
  auto loadC = [&](int4 (&c)[8], float (&ax)[2], int kb) {
    const int* p0 = qrow0 + kb * 64;
    const int* p1 = qrow1 + kb * 64;
    c[0] = *(const int4*)(p0);      c[1] = *(const int4*)(p0 + 4);
    c[2] = *(const int4*)(p0 + 32); c[3] = *(const int4*)(p0 + 36);
    c[4] = *(const int4*)(p1);      c[5] = *(const int4*)(p1 + 4);
    c[6] = *(const int4*)(p1 + 32); c[7] = *(const int4*)(p1 + 36);
    ax[0] = arow0[kb];
    ax[1] = arow1[kb];
  };
  // batch-issue all 16 A-frags of one k-block (a[mt*2+ks2])
  auto issueA = [&](f16x8 (&a)[16], int kb) {
#pragma unroll
    for (int mt = 0; mt < 8; ++mt)
#pragma unroll
      for (int ks2 = 0; ks2 < 2; ++ks2)
        a[mt * 2 + ks2] = *(const f16x8*)(
            xf + (((size_t)kb * 4 + wm * 2 + (mt >> 2)) * 8 + (mt & 3) * 2 + ks2) * 512 + l * 8);
  };
  auto dqB = [&](const int4 (&c)[8], const float (&ax)[2], f16x8 (&b)[2][2]) {
#pragma unroll
    for (int nt = 0; nt < 2; ++nt) {
      __half2 ax2 = __float2half2_rn(ax[nt]);
#pragma unroll
      for (int ks2 = 0; ks2 < 2; ++ks2) {
        union { uint2 u2[2]; f16x8 f; } u;
        u.u2[0] = dq4(c[nt * 4 + ks2 * 2 + 0], ax2, tbits);
        u.u2[1] = dq4(c[nt * 4 + ks2 * 2 + 1], ax2, tbits);
        b[nt][ks2] = u.f;
      }
    }
  };
  auto mfma32 = [&](const f16x8 (&a)[16], const f16x8 (&b)[2][2]) {
    __builtin_amdgcn_s_setprio(1);
#pragma unroll
    for (int ks2 = 0; ks2 < 2; ++ks2)
#pragma unroll
      for (int mt = 0; mt < 8; ++mt)
#pragma unroll
        for (int nt = 0; nt < 2; ++nt)
          acc[mt][nt] = __builtin_amdgcn_mfma_f32_16x16x32_f16(
              a[mt * 2 + ks2], b[nt][ks2], acc[mt][nt], 0, 0, 0);
    __builtin_amdgcn_s_setprio(0);
  };

  int4 cA[8], cB[8];
  float axA[2], axB[2];
  f16x8 aF[16];
  loadC(cA, axA, kb0);
  if (nst > 1) loadC(cB, axB, kb0 + 1);

  for (int s = 0; s < nst; s += 2) {
    {
      issueA(aF, kb0 + s);
      f16x8 b[2][2];
      dqB(cA, axA, b);                               // covers A's L2 latency
      if (s + 2 < nst) loadC(cA, axA, kb0 + s + 2);  // refill HBM code dbuf
      mfma32(aF, b);                                 // single wait, 32 MFMAs
    }
    if (s + 1 < nst) {
      issueA(aF, kb0 + s + 1);
      f16x8 b[2][2];
      dqB(cB, axB, b);
      if (s + 3 < nst) loadC(cB, axB, kb0 + s + 3);
      mfma32(aF, b);
    }
  }

  if (split == 0) {
    // lora K-extension: k in [0,32) (rank 16 + zero pad); register frags
    f16x8 b_l[2];
    b_l[0] = *(const f16x8*)(lBh + (size_t)(nw0 + rlo) * 64 + chunk * 8);
    b_l[1] = *(const f16x8*)(lBh + (size_t)(nw0 + 16 + rlo) * 64 + chunk * 8);
#pragma unroll
    for (int mt = 0; mt < 8; ++mt) {
      f16x8 a_l = *(const f16x8*)(xa2 + (size_t)(wm * 128 + mt * 16 + rlo) * 64 + chunk * 8);
#pragma unroll
      for (int nt = 0; nt < 2; ++nt)
        acc[mt][nt] = __builtin_amdgcn_mfma_f32_16x16x32_f16(a_l, b_l[nt], acc[mt][nt], 0, 0, 0);
    }
  }

  // epilogue: C/D layout col=lane&15 -> nw0+nt*16+rlo, row = wm*128+mt*16+chunk*4+r
  if (fp16out) {
    ushort* dst = dest16 + (size_t)split * TOK * OUTF;
#pragma unroll
    for (int mt = 0; mt < 8; ++mt)
#pragma unroll
      for (int nt = 0; nt < 2; ++nt) {
        int c = nw0 + nt * 16 + rlo;
#pragma unroll
        for (int r = 0; r < 4; ++r)
          dst[(size_t)(wm * 128 + mt * 16 + chunk * 4 + r) * OUTF + c] = f2h(acc[mt][nt][r]);
      }
  } else {
    float* dst = dest32;
#pragma unroll
    for (int mt = 0; mt < 8; ++mt)
#pragma unroll
      for (int nt = 0; nt < 2; ++nt) {
        int c = nw0 + nt * 16 + rlo;
#pragma unroll
        for (int r = 0; r < 4; ++r)
          dst[(size_t)(wm * 128 + mt * 16 + chunk * 4 + r) * OUTF + c] = acc[mt][nt][r];
      }
  }
}

// kernel 4: sum f16 K-split partials -> f32 out; 8 halfs (uint4) per thread
__global__ void reduce_kernel(const uint4* __restrict__ part, float4* __restrict__ out,
                              int ks) {
  const int QN8 = TOK * OUTF / 8;
  int i = blockIdx.x * blockDim.x + threadIdx.x;
  if (i < QN8) {
    float s0 = 0.f, s1 = 0.f, s2 = 0.f, s3 = 0.f, s4 = 0.f, s5 = 0.f, s6 = 0.f, s7 = 0.f;
    for (int sp = 0; sp < ks; ++sp) {
      uint4 v = part[(size_t)sp * QN8 + i];
      union { uint u; __half2 h; } a, b, c, d;
      a.u = v.x; b.u = v.y; c.u = v.z; d.u = v.w;
      float2 fa = __half22float2(a.h), fb = __half22float2(b.h);
      float2 fc = __half22float2(c.h), fd = __half22float2(d.h);
      s0 += fa.x; s1 += fa.y; s2 += fb.x; s3 += fb.y;
      s4 += fc.x; s5 += fc.y; s6 += fd.x; s7 += fd.y;
    }
    out[2 * i] = (float4){s0, s1, s2, s3};
    out[2 * i + 1] = (float4){s4, s5, s6, s7};
  }
}

extern "C" void kernel_launch(void* const* d_in, const int* in_sizes, int n_in,
                              void* d_out, int out_size, void* d_ws, size_t ws_size,
                              hipStream_t stream) {
  const float* x = (const float*)d_in[0];
  const int* qc = (const int*)d_in[1];
  const float* am = (const float*)d_in[2];
  const float* lA = (const float*)d_in[3];
  const float* lB = (const float*)d_in[4];
  float* out = (float*)d_out;

  const size_t off_lB = (size_t)TOK * INF * 2;              // 2.10 MB (xf)
  const size_t off_xa2 = off_lB + (size_t)OUTF * 64 * 2;    // +1.41 MB
  const size_t off_part = off_xa2 + (size_t)TOK * 64 * 2;   // +32 KB
  const size_t part_bytes = (size_t)TOK * OUTF * 2;         // 5.63 MB per split (f16)

  ushort* xf = (ushort*)d_ws;
  ushort* lBh = (ushort*)((char*)d_ws + off_lB);
  ushort* xa2 = (ushort*)((char*)d_ws + off_xa2);
  ushort* part = (ushort*)((char*)d_ws + off_part);

  int ks = 1;
  if (ws_size >= off_part + 8 * part_bytes) ks = 8;       // ws ~688 MB -> ks=8
  else if (ws_size >= off_part + 4 * part_bytes) ks = 4;
  else if (ws_size >= off_part + 2 * part_bytes) ks = 2;
  const int fp16out = (ks > 1) ? 1 : 0;

  prep_kernel<<<2048, 256, 0, stream>>>(x, (uint4*)xf, (const float4*)lB,
                                        (ushort4*)lBh);
  xa_kernel<<<TOK, 1024, 0, stream>>>(x, lA, xa2);
  gemm_kernel<<<NT2 * ks, 256, 0, stream>>>(qc, am, xf, lBh, xa2, out, part,
                                            64 / ks, fp16out);
  if (ks > 1)
    reduce_kernel<<<(TOK * OUTF / 8 + 255) / 256, 256, 0, stream>>>((const uint4*)part,
                                                                    (float4*)out, ks);
}